// Round 14
// baseline (55.097 us; speedup 1.0000x reference)
//
#include <hip/hip_runtime.h>

#define NB   16
#define NC   3
#define NH   512
#define NW   512
#define OUTH 506
#define OUTW 506
#define NCHK 21          // 19 chunks x 24 rows + 2 chunks x 25 rows = 506
#define NSLOT 10
#define NBLK (NB * NC * NCHK)   // 1008 blocks (<= 1024 resident, 4/CU via 40KB LDS)
#define BPI  (NC * NCHK)        // 63 partials per image
#define MMB  64

typedef float v2f __attribute__((ext_vector_type(2)));
typedef float v4f __attribute__((ext_vector_type(4)));
#define LO(v) __builtin_shufflevector(v, v, 0, 1)
#define HI(v) __builtin_shufflevector(v, v, 2, 3)

// LDS-visibility barrier WITHOUT the vmcnt(0) drain of __syncthreads()
#define LDS_BARRIER() do {                                   \
        asm volatile("s_waitcnt lgkmcnt(0)" ::: "memory");   \
        __builtin_amdgcn_s_barrier();                        \
    } while (0)

// -------- kernel 1: per-image min/max partials (no atomics)
__global__ __launch_bounds__(256) void ssim_minmax(const float* __restrict__ pred,
                                                   float* __restrict__ mnp,
                                                   float* __restrict__ mxp) {
    int b = blockIdx.y;
    const float4* p4 = (const float4*)(pred + (size_t)b * (NC * NH * NW));
    const int n4 = (NC * NH * NW) / 4;
    float lmin = 3.4e38f, lmax = -3.4e38f;
    for (int i = blockIdx.x * blockDim.x + threadIdx.x; i < n4; i += gridDim.x * blockDim.x) {
        float4 v = p4[i];
        lmin = fminf(lmin, fminf(fminf(v.x, v.y), fminf(v.z, v.w)));
        lmax = fmaxf(lmax, fmaxf(fmaxf(v.x, v.y), fmaxf(v.z, v.w)));
    }
    #pragma unroll
    for (int off = 32; off; off >>= 1) {
        lmin = fminf(lmin, __shfl_down(lmin, off, 64));
        lmax = fmaxf(lmax, __shfl_down(lmax, off, 64));
    }
    __shared__ float smin[4], smax[4];
    int wid = threadIdx.x >> 6, lane = threadIdx.x & 63;
    if (lane == 0) { smin[wid] = lmin; smax[wid] = lmax; }
    __syncthreads();
    if (threadIdx.x == 0) {
        mnp[b * MMB + blockIdx.x] = fminf(fminf(smin[0], smin[1]), fminf(smin[2], smin[3]));
        mxp[b * MMB + blockIdx.x] = fmaxf(fmaxf(smax[0], smax[1]), fmaxf(smax[2], smax[3]));
    }
}

// -------- kernel 2: LDS-ring SSIM (R11 base: 2 waves, 512 cols, 4 cols/thread)
// + compile-time ring slots (10-step unrolled groups -> ds offsets are imms)
// + packed-fp32 accumulators (v_pk_fma_f32 class)
// + lgkm-only barrier (global loads stay in flight across iters)
// Ring algebra (verified R9-R11): iter k enters slot k%10 (prefetched at k-1
// from slot (k%10+1)%10... i.e. sn), leaves slot (k+3)%10 (row k-7), writes
// slot (k+2)%10 (row k+2, loaded at iter k-1). Written slot's last read was
// the leave at iter k-1 -> barrier-separated.
__global__ __launch_bounds__(128) void ssim_main(const float* __restrict__ tin,
                                                 const float* __restrict__ pin,
                                                 const float* __restrict__ mnp,
                                                 const float* __restrict__ mxp,
                                                 float* __restrict__ bsum) {
    __shared__ float ring[NSLOT][2][NW];   // 40,960 B -> 4 blocks/CU

    const int li    = threadIdx.x;          // 0..127
    const int lane  = li & 63;
    const int imgch = blockIdx.x / NCHK;
    const int chunk = blockIdx.x - imgch * NCHK;
    const int b     = imgch / NC;
    const int r0    = chunk * 24 + max(0, chunk - 19);  // chunks 19,20: 25 rows
    const int rpc   = (chunk >= 19) ? 25 : 24;
    const int kend  = rpc + 6;               // 30 or 31
    const int lastr = rpc + 5;

    // per-image range from 64 partials: butterfly, no LDS
    float mnv = mnp[b * MMB + lane], mxv = mxp[b * MMB + lane];
    #pragma unroll
    for (int m = 1; m < 64; m <<= 1) {
        mnv = fminf(mnv, __shfl_xor(mnv, m, 64));
        mxv = fmaxf(mxv, __shfl_xor(mxv, m, 64));
    }
    const float dr  = mxv - mnv;
    const float c1  = (0.01f * dr) * (0.01f * dr);
    const float c2  = (0.03f * dr) * (0.03f * dr);
    const float C1s = 2401.0f * c1;   // 49^2 * c1
    const float C2s = 2352.0f * c2;   // 48*49 * c2

    const float* tbase = tin + (size_t)imgch * (NH * NW) + (size_t)r0 * NW;
    const float* pbase = pin + (size_t)imgch * (NH * NW) + (size_t)r0 * NW;

    // staging: thread li stages one t-float4 AND one p-float4 (cols 4li..4li+3)
    const int scol = 4 * li;                 // 0..508

    // compute ownership: own cols rc..rc+3, track rc..rc+9 (+2 slack)
    const int rc  = 4 * li;
    const int cb1 = min(rc + 4, NW - 4);
    const int cb2 = min(rc + 8, NW - 4);

    v2f A1[5], A2[5], A3[5], A4[5], A5[5];
    {
        const v2f vz = {0.f, 0.f};
        #pragma unroll
        for (int i = 0; i < 5; ++i) { A1[i]=vz; A2[i]=vz; A3[i]=vz; A4[i]=vz; A5[i]=vz; }
    }
    float acc = 0.f;

#define LOADT(T0, T1, T2, P0, P1, P2, S) do {                       \
        T0 = *(const v4f*)&ring[S][0][rc];                          \
        T1 = *(const v4f*)&ring[S][0][cb1];                         \
        T2 = *(const v4f*)&ring[S][0][cb2];                         \
        P0 = *(const v4f*)&ring[S][1][rc];                          \
        P1 = *(const v4f*)&ring[S][1][cb1];                         \
        P2 = *(const v4f*)&ring[S][1][cb2];                         \
    } while (0)

#define UPDP(J, T_, P_) do {                                        \
        v2f t_ = T_, p_ = P_;                                       \
        A1[J] += t_; A2[J] += p_;                                   \
        A3[J] = __builtin_elementwise_fma(t_, t_, A3[J]);           \
        A4[J] = __builtin_elementwise_fma(p_, p_, A4[J]);           \
        A5[J] = __builtin_elementwise_fma(t_, p_, A5[J]);           \
    } while (0)

#define UPDN(J, T_, P_) do {                                        \
        v2f t_ = T_, p_ = P_;                                       \
        A1[J] -= t_; A2[J] -= p_;                                   \
        A3[J] = __builtin_elementwise_fma(-t_, t_, A3[J]);          \
        A4[J] = __builtin_elementwise_fma(-p_, p_, A4[J]);          \
        A5[J] = __builtin_elementwise_fma(-t_, p_, A5[J]);          \
    } while (0)

#define APPLYP(T0,T1,T2,P0,P1,P2) do {                              \
        UPDP(0, LO(T0), LO(P0)); UPDP(1, HI(T0), HI(P0));           \
        UPDP(2, LO(T1), LO(P1)); UPDP(3, HI(T1), HI(P1));           \
        UPDP(4, LO(T2), LO(P2));                                    \
    } while (0)

#define APPLYN(T0,T1,T2,P0,P1,P2) do {                              \
        UPDN(0, LO(T0), LO(P0)); UPDN(1, HI(T0), HI(P0));           \
        UPDN(2, LO(T1), LO(P1)); UPDN(3, HI(T1), HI(P1));           \
        UPDN(4, LO(T2), LO(P2));                                    \
    } while (0)

#define EL(A, I) (((I) & 1) ? A[(I) >> 1].y : A[(I) >> 1].x)

#define SSIMADD(C) do {                                             \
        if (rc + (C) < OUTW) {                                      \
            float p12 = S1 * S2;                                    \
            float q1  = S1 * S1, q2 = S2 * S2;                      \
            float Aa  = fmaf(2.f, p12, C1s);                        \
            float Bb  = q1 + q2 + C1s;                              \
            float mtp = fmaf(49.f, S5, -p12);                       \
            float Ac  = fmaf(2.f, mtp, C2s);                        \
            float mtt = fmaf(49.f, S3, -q1);                        \
            float mpp = fmaf(49.f, S4, -q2);                        \
            float Bd  = mtt + mpp + C2s;                            \
            acc += __fdividef(Aa * Ac, Bb * Bd);                    \
        }                                                           \
    } while (0)

#define EMIT do {                                                   \
        float S1 = EL(A1,0)+EL(A1,1)+EL(A1,2)+EL(A1,3)+EL(A1,4)+EL(A1,5)+EL(A1,6); \
        float S2 = EL(A2,0)+EL(A2,1)+EL(A2,2)+EL(A2,3)+EL(A2,4)+EL(A2,5)+EL(A2,6); \
        float S3 = EL(A3,0)+EL(A3,1)+EL(A3,2)+EL(A3,3)+EL(A3,4)+EL(A3,5)+EL(A3,6); \
        float S4 = EL(A4,0)+EL(A4,1)+EL(A4,2)+EL(A4,3)+EL(A4,4)+EL(A4,5)+EL(A4,6); \
        float S5 = EL(A5,0)+EL(A5,1)+EL(A5,2)+EL(A5,3)+EL(A5,4)+EL(A5,5)+EL(A5,6); \
        SSIMADD(0);                                                 \
        _Pragma("unroll")                                           \
        for (int c = 1; c < 4; ++c) {                               \
            S1 += EL(A1,c+6) - EL(A1,c-1);                          \
            S2 += EL(A2,c+6) - EL(A2,c-1);                          \
            S3 += EL(A3,c+6) - EL(A3,c-1);                          \
            S4 += EL(A4,c+6) - EL(A4,c-1);                          \
            S5 += EL(A5,c+6) - EL(A5,c-1);                          \
            SSIMADD(c);                                             \
        }                                                           \
    } while (0)

    // STEP: SE is a LITERAL slot (K % 10); parity of K picks load/stage sets.
#define STEP_IMPL(K, SE, GLT, GLP, GST, GSP) do {                   \
        /* 1) stage row K+2 (regs loaded at iter K-1) */            \
        if ((K) + 2 <= lastr) {                                     \
            *(v4f*)&ring[(SE + 2) % NSLOT][0][scol] = GST;          \
            *(v4f*)&ring[(SE + 2) % NSLOT][1][scol] = GSP;          \
        }                                                           \
        /* 2) load row K+3 (in flight across lgkm barrier) */       \
        if ((K) + 3 <= lastr) {                                     \
            GLT = *(const v4f*)(tbase + (size_t)((K) + 3) * NW + scol); \
            GLP = *(const v4f*)(pbase + (size_t)((K) + 3) * NW + scol); \
        }                                                           \
        /* 3) leave-reads issued early (hidden under enter-apply) */ \
        v4f lt0, lt1, lt2, lp0, lp1, lp2;                           \
        if ((K) >= 7) LOADT(lt0,lt1,lt2,lp0,lp1,lp2,(SE + 3) % NSLOT); \
        /* 4) enter row K from prefetched regs */                   \
        APPLYP(et0,et1,et2,ep0,ep1,ep2);                            \
        /* 5) prefetch enter row K+1 */                             \
        if ((K) + 1 < kend) LOADT(et0,et1,et2,ep0,ep1,ep2,(SE + 1) % NSLOT); \
        /* 6) leave row K-7 */                                      \
        if ((K) >= 7) APPLYN(lt0,lt1,lt2,lp0,lp1,lp2);              \
        /* 7) emit row K-6 */                                       \
        if ((K) >= 6) { EMIT; }                                     \
        LDS_BARRIER();                                              \
    } while (0)

    // prologue: rows 0,1 staged; row 2 -> set B (stage at iter 0)
    v4f gtA, gpA, gtB, gpB;
    {
        v4f t0 = *(const v4f*)(tbase + scol);
        v4f p0 = *(const v4f*)(pbase + scol);
        *(v4f*)&ring[0][0][scol] = t0;
        *(v4f*)&ring[0][1][scol] = p0;
        v4f t1 = *(const v4f*)(tbase + NW + scol);
        v4f p1 = *(const v4f*)(pbase + NW + scol);
        *(v4f*)&ring[1][0][scol] = t1;
        *(v4f*)&ring[1][1][scol] = p1;
    }
    gtB = *(const v4f*)(tbase + 2 * NW + scol);
    gpB = *(const v4f*)(pbase + 2 * NW + scol);
    __syncthreads();

    v4f et0, et1, et2, ep0, ep1, ep2;
    LOADT(et0,et1,et2,ep0,ep1,ep2, 0);       // enter row 0

    // 3 groups of 10 steps: slots are literals, parity alternates sets
    int kb = 0;
    #pragma unroll 1
    for (int g = 0; g < 3; ++g, kb += 10) {
        STEP_IMPL(kb + 0, 0, gtA, gpA, gtB, gpB);
        STEP_IMPL(kb + 1, 1, gtB, gpB, gtA, gpA);
        STEP_IMPL(kb + 2, 2, gtA, gpA, gtB, gpB);
        STEP_IMPL(kb + 3, 3, gtB, gpB, gtA, gpA);
        STEP_IMPL(kb + 4, 4, gtA, gpA, gtB, gpB);
        STEP_IMPL(kb + 5, 5, gtB, gpB, gtA, gpA);
        STEP_IMPL(kb + 6, 6, gtA, gpA, gtB, gpB);
        STEP_IMPL(kb + 7, 7, gtB, gpB, gtA, gpA);
        STEP_IMPL(kb + 8, 8, gtA, gpA, gtB, gpB);
        STEP_IMPL(kb + 9, 9, gtB, gpB, gtA, gpA);
    }
    if (kend == 31) { STEP_IMPL(30, 0, gtA, gpA, gtB, gpB); }

#undef STEP_IMPL
#undef EMIT
#undef SSIMADD
#undef EL
#undef APPLYN
#undef APPLYP
#undef UPDN
#undef UPDP
#undef LOADT

    // per-block partial (deterministic); ring is dead
    #pragma unroll
    for (int off = 32; off; off >>= 1) acc += __shfl_down(acc, off, 64);
    if (lane == 0) ((float*)ring)[li >> 6] = acc;
    __syncthreads();
    if (li == 0) {
        float* r = (float*)ring;
        bsum[blockIdx.x] = r[0] + r[1];
    }
}

// -------- kernel 3: finalize per-image mean from 63 block partials
__global__ void ssim_finalize(const float* __restrict__ bsum, float* __restrict__ out) {
    int b = blockIdx.x, lane = threadIdx.x;   // 64 threads
    float v = (lane < BPI) ? bsum[b * BPI + lane] : 0.0f;
    #pragma unroll
    for (int off = 32; off; off >>= 1) v += __shfl_down(v, off, 64);
    if (lane == 0) out[b] = v / (float)(NC * OUTH * OUTW);
}

extern "C" void kernel_launch(void* const* d_in, const int* in_sizes, int n_in,
                              void* d_out, int out_size, void* d_ws, size_t ws_size,
                              hipStream_t stream) {
    const float* t = (const float*)d_in[0];   // true
    const float* p = (const float*)d_in[1];   // pred
    float* out = (float*)d_out;

    float* mnp  = (float*)d_ws;               // 1024 floats
    float* mxp  = mnp + NB * MMB;             // 1024 floats
    float* bsum = mxp + NB * MMB;             // 1008 floats

    ssim_minmax<<<dim3(MMB, NB), 256, 0, stream>>>(p, mnp, mxp);
    // 1008 two-wave blocks (16 img x 3 ch x 21 row-chunks), 40 KB LDS
    ssim_main<<<dim3(NBLK), 128, 0, stream>>>(t, p, mnp, mxp, bsum);
    ssim_finalize<<<dim3(NB), 64, 0, stream>>>(bsum, out);
}

// Round 15
// 55.075 us; speedup vs baseline: 1.0004x; 1.0004x over previous
//
#include <hip/hip_runtime.h>

#define NB   16
#define NC   3
#define NH   512
#define NW   512
#define OUTH 506
#define OUTW 506
#define NCHK 21          // 19 chunks x 24 rows + 2 chunks x 25 rows = 506
#define NSLOT 10
#define NBLK (NB * NC * NCHK)   // 1008 blocks (4/CU via 40KB LDS, all resident)
#define BPI  (NC * NCHK)        // 63 partials per image
#define MMB  64

// LDS-visibility barrier WITHOUT the vmcnt(0) drain of __syncthreads()
#define LDS_BARRIER() do {                                   \
        asm volatile("s_waitcnt lgkmcnt(0)" ::: "memory");   \
        __builtin_amdgcn_s_barrier();                        \
    } while (0)

// -------- kernel 1: per-image min/max partials (no atomics)
__global__ __launch_bounds__(256) void ssim_minmax(const float* __restrict__ pred,
                                                   float* __restrict__ mnp,
                                                   float* __restrict__ mxp) {
    int b = blockIdx.y;
    const float4* p4 = (const float4*)(pred + (size_t)b * (NC * NH * NW));
    const int n4 = (NC * NH * NW) / 4;
    float lmin = 3.4e38f, lmax = -3.4e38f;
    for (int i = blockIdx.x * blockDim.x + threadIdx.x; i < n4; i += gridDim.x * blockDim.x) {
        float4 v = p4[i];
        lmin = fminf(lmin, fminf(fminf(v.x, v.y), fminf(v.z, v.w)));
        lmax = fmaxf(lmax, fmaxf(fmaxf(v.x, v.y), fmaxf(v.z, v.w)));
    }
    #pragma unroll
    for (int off = 32; off; off >>= 1) {
        lmin = fminf(lmin, __shfl_down(lmin, off, 64));
        lmax = fmaxf(lmax, __shfl_down(lmax, off, 64));
    }
    __shared__ float smin[4], smax[4];
    int wid = threadIdx.x >> 6, lane = threadIdx.x & 63;
    if (lane == 0) { smin[wid] = lmin; smax[wid] = lmax; }
    __syncthreads();
    if (threadIdx.x == 0) {
        mnp[b * MMB + blockIdx.x] = fminf(fminf(smin[0], smin[1]), fminf(smin[2], smin[3]));
        mxp[b * MMB + blockIdx.x] = fmaxf(fmaxf(smax[0], smax[1]), fmaxf(smax[2], smax[3]));
    }
}

// -------- kernel 2: R11 structure + compile-time ring slots + lgkm barrier
// 2 waves, 512 cols, thread owns 4 cols / tracks 10, all ds ops b128.
// 10-step unrolled groups make every ring[S] a literal -> ds offset imms.
// Ring algebra (verified R9-R11, passing): iter K enters slot K%10
// (prefetched at K-1), leaves slot (K+3)%10 (row K-7), stages slot (K+2)%10
// (row K+2, loaded at K-1). Written slot's last read = leave at K-1,
// barrier-separated.
__global__ __launch_bounds__(128) void ssim_main(const float* __restrict__ tin,
                                                 const float* __restrict__ pin,
                                                 const float* __restrict__ mnp,
                                                 const float* __restrict__ mxp,
                                                 float* __restrict__ bsum) {
    __shared__ float ring[NSLOT][2][NW];   // 40,960 B -> 4 blocks/CU

    const int li    = threadIdx.x;          // 0..127
    const int lane  = li & 63;
    const int imgch = blockIdx.x / NCHK;
    const int chunk = blockIdx.x - imgch * NCHK;
    const int b     = imgch / NC;
    const int r0    = chunk * 24 + max(0, chunk - 19);  // chunks 19,20: 25 rows
    const int rpc   = (chunk >= 19) ? 25 : 24;
    const int kend  = rpc + 6;               // 30 or 31
    const int lastr = rpc + 5;

    // per-image range from 64 partials: butterfly, no LDS
    float mnv = mnp[b * MMB + lane], mxv = mxp[b * MMB + lane];
    #pragma unroll
    for (int m = 1; m < 64; m <<= 1) {
        mnv = fminf(mnv, __shfl_xor(mnv, m, 64));
        mxv = fmaxf(mxv, __shfl_xor(mxv, m, 64));
    }
    const float dr  = mxv - mnv;
    const float c1  = (0.01f * dr) * (0.01f * dr);
    const float c2  = (0.03f * dr) * (0.03f * dr);
    const float C1s = 2401.0f * c1;   // 49^2 * c1
    const float C2s = 2352.0f * c2;   // 48*49 * c2

    const float* tbase = tin + (size_t)imgch * (NH * NW) + (size_t)r0 * NW;
    const float* pbase = pin + (size_t)imgch * (NH * NW) + (size_t)r0 * NW;

    // staging: thread li stages t and p float4 at cols 4li..4li+3
    const int scol = 4 * li;                 // 0..508
    // compute: own cols rc..rc+3, track rc..rc+9 (clamped slots feed only
    // masked outputs; verified passing R11)
    const int rc  = 4 * li;
    const int cb1 = min(rc + 4, NW - 4);
    const int cb2 = min(rc + 8, NW - 4);

    float st[10], sp[10], stt[10], spp[10], stp[10];
    #pragma unroll
    for (int i = 0; i < 10; ++i) { st[i]=0.f; sp[i]=0.f; stt[i]=0.f; spp[i]=0.f; stp[i]=0.f; }
    float acc = 0.f;

#define LOADT(TE, PE, S) do {                                       \
        *(float4*)&TE[0] = *(const float4*)&ring[S][0][rc];         \
        *(float4*)&TE[4] = *(const float4*)&ring[S][0][cb1];        \
        *(float4*)&TE[8] = *(const float4*)&ring[S][0][cb2];        \
        *(float4*)&PE[0] = *(const float4*)&ring[S][1][rc];         \
        *(float4*)&PE[4] = *(const float4*)&ring[S][1][cb1];        \
        *(float4*)&PE[8] = *(const float4*)&ring[S][1][cb2];        \
    } while (0)

#define APPLY(TE, PE, SGN) do {                                     \
        _Pragma("unroll")                                           \
        for (int i = 0; i < 10; ++i) {                              \
            float t_ = TE[i], p_ = PE[i];                           \
            st[i] += SGN t_;  sp[i] += SGN p_;                      \
            stt[i] = fmaf(SGN t_, t_, stt[i]);                      \
            spp[i] = fmaf(SGN p_, p_, spp[i]);                      \
            stp[i] = fmaf(SGN t_, p_, stp[i]);                      \
        }                                                           \
    } while (0)

#define SSIMADD(C) do {                                             \
        if (rc + (C) < OUTW) {                                      \
            float p12 = S1 * S2;                                    \
            float q1  = S1 * S1, q2 = S2 * S2;                      \
            float Aa  = fmaf(2.f, p12, C1s);                        \
            float Bb  = q1 + q2 + C1s;                              \
            float mtp = fmaf(49.f, S5, -p12);                       \
            float Ac  = fmaf(2.f, mtp, C2s);                        \
            float mtt = fmaf(49.f, S3, -q1);                        \
            float mpp = fmaf(49.f, S4, -q2);                        \
            float Bd  = mtt + mpp + C2s;                            \
            acc += __fdividef(Aa * Ac, Bb * Bd);                    \
        }                                                           \
    } while (0)

#define EMIT do {                                                   \
        float S1 = st[0]+st[1]+st[2]+st[3]+st[4]+st[5]+st[6];       \
        float S2 = sp[0]+sp[1]+sp[2]+sp[3]+sp[4]+sp[5]+sp[6];       \
        float S3 = stt[0]+stt[1]+stt[2]+stt[3]+stt[4]+stt[5]+stt[6];\
        float S4 = spp[0]+spp[1]+spp[2]+spp[3]+spp[4]+spp[5]+spp[6];\
        float S5 = stp[0]+stp[1]+stp[2]+stp[3]+stp[4]+stp[5]+stp[6];\
        SSIMADD(0);                                                 \
        _Pragma("unroll")                                           \
        for (int c = 1; c < 4; ++c) {                               \
            S1 += st[c+6]  - st[c-1];                               \
            S2 += sp[c+6]  - sp[c-1];                               \
            S3 += stt[c+6] - stt[c-1];                              \
            S4 += spp[c+6] - spp[c-1];                              \
            S5 += stp[c+6] - stp[c-1];                              \
            SSIMADD(c);                                             \
        }                                                           \
    } while (0)

    // STEP: SE is a literal (K % 10) -> all ring[] addresses constant-fold.
#define STEP_IMPL(K, SE, GLT, GLP, GST, GSP) do {                   \
        /* 1) stage row K+2 (regs loaded at iter K-1) */            \
        if ((K) + 2 <= lastr) {                                     \
            *(float4*)&ring[(SE + 2) % NSLOT][0][scol] = GST;       \
            *(float4*)&ring[(SE + 2) % NSLOT][1][scol] = GSP;       \
        }                                                           \
        /* 2) load row K+3 (stays in flight across lgkm barrier) */ \
        if ((K) + 3 <= lastr) {                                     \
            GLT = *(const float4*)(tbase + (size_t)((K) + 3) * NW + scol); \
            GLP = *(const float4*)(pbase + (size_t)((K) + 3) * NW + scol); \
        }                                                           \
        /* 3) leave-reads issued early (hidden under enter-apply) */ \
        float lt[12], lp[12];                                       \
        if ((K) >= 7) LOADT(lt, lp, (SE + 3) % NSLOT);              \
        /* 4) enter row K from prefetched regs */                   \
        APPLY(et, ep, +);                                           \
        /* 5) prefetch enter row K+1 (staged at iter K-1) */        \
        if ((K) + 1 < kend) LOADT(et, ep, (SE + 1) % NSLOT);        \
        /* 6) leave row K-7 */                                      \
        if ((K) >= 7) APPLY(lt, lp, -);                             \
        /* 7) emit row K-6 */                                       \
        if ((K) >= 6) { EMIT; }                                     \
        LDS_BARRIER();                                              \
    } while (0)

    // prologue: rows 0,1 staged; row 2 -> set B (staged at iter 0)
    float4 gtA, gpA, gtB, gpB;
    {
        float4 t0 = *(const float4*)(tbase + scol);
        float4 p0 = *(const float4*)(pbase + scol);
        *(float4*)&ring[0][0][scol] = t0;
        *(float4*)&ring[0][1][scol] = p0;
        float4 t1 = *(const float4*)(tbase + NW + scol);
        float4 p1 = *(const float4*)(pbase + NW + scol);
        *(float4*)&ring[1][0][scol] = t1;
        *(float4*)&ring[1][1][scol] = p1;
    }
    gtB = *(const float4*)(tbase + 2 * NW + scol);
    gpB = *(const float4*)(pbase + 2 * NW + scol);
    __syncthreads();

    float et[12], ep[12];
    LOADT(et, ep, 0);                        // enter row 0

    // 3 groups of 10 steps: slots are literals, parity alternates G-sets
    int kb = 0;
    #pragma unroll 1
    for (int g = 0; g < 3; ++g, kb += 10) {
        STEP_IMPL(kb + 0, 0, gtA, gpA, gtB, gpB);
        STEP_IMPL(kb + 1, 1, gtB, gpB, gtA, gpA);
        STEP_IMPL(kb + 2, 2, gtA, gpA, gtB, gpB);
        STEP_IMPL(kb + 3, 3, gtB, gpB, gtA, gpA);
        STEP_IMPL(kb + 4, 4, gtA, gpA, gtB, gpB);
        STEP_IMPL(kb + 5, 5, gtB, gpB, gtA, gpA);
        STEP_IMPL(kb + 6, 6, gtA, gpA, gtB, gpB);
        STEP_IMPL(kb + 7, 7, gtB, gpB, gtA, gpA);
        STEP_IMPL(kb + 8, 8, gtA, gpA, gtB, gpB);
        STEP_IMPL(kb + 9, 9, gtB, gpB, gtA, gpA);
    }
    if (kend == 31) { STEP_IMPL(30, 0, gtA, gpA, gtB, gpB); }

#undef STEP_IMPL
#undef EMIT
#undef SSIMADD
#undef APPLY
#undef LOADT

    // per-block partial (deterministic); ring is dead
    #pragma unroll
    for (int off = 32; off; off >>= 1) acc += __shfl_down(acc, off, 64);
    if (lane == 0) ((float*)ring)[li >> 6] = acc;
    __syncthreads();
    if (li == 0) {
        float* r = (float*)ring;
        bsum[blockIdx.x] = r[0] + r[1];
    }
}

// -------- kernel 3: finalize per-image mean from 63 block partials
__global__ void ssim_finalize(const float* __restrict__ bsum, float* __restrict__ out) {
    int b = blockIdx.x, lane = threadIdx.x;   // 64 threads
    float v = (lane < BPI) ? bsum[b * BPI + lane] : 0.0f;
    #pragma unroll
    for (int off = 32; off; off >>= 1) v += __shfl_down(v, off, 64);
    if (lane == 0) out[b] = v / (float)(NC * OUTH * OUTW);
}

extern "C" void kernel_launch(void* const* d_in, const int* in_sizes, int n_in,
                              void* d_out, int out_size, void* d_ws, size_t ws_size,
                              hipStream_t stream) {
    const float* t = (const float*)d_in[0];   // true
    const float* p = (const float*)d_in[1];   // pred
    float* out = (float*)d_out;

    float* mnp  = (float*)d_ws;               // 1024 floats
    float* mxp  = mnp + NB * MMB;             // 1024 floats
    float* bsum = mxp + NB * MMB;             // 1008 floats

    ssim_minmax<<<dim3(MMB, NB), 256, 0, stream>>>(p, mnp, mxp);
    // 1008 two-wave blocks (16 img x 3 ch x 21 row-chunks), 40 KB LDS
    ssim_main<<<dim3(NBLK), 128, 0, stream>>>(t, p, mnp, mxp, bsum);
    ssim_finalize<<<dim3(NB), 64, 0, stream>>>(bsum, out);
}

// Round 16
// 49.518 us; speedup vs baseline: 1.1127x; 1.1122x over previous
//
#include <hip/hip_runtime.h>

#define NB   16
#define NC   3
#define NH   512
#define NW   512
#define OUTH 506
#define OUTW 506
#define NCHK 21          // 19 chunks x 24 rows + 2 chunks x 25 rows = 506
#define NSLOT 10
#define NBLK (NB * NC * NCHK)   // 1008 blocks (4/CU via 40KB LDS)
#define BPI  (NC * NCHK)        // 63 partials per image
#define MMB  64

// -------- kernel 1: per-image min/max partials (no atomics)
__global__ __launch_bounds__(256) void ssim_minmax(const float* __restrict__ pred,
                                                   float* __restrict__ mnp,
                                                   float* __restrict__ mxp) {
    int b = blockIdx.y;
    const float4* p4 = (const float4*)(pred + (size_t)b * (NC * NH * NW));
    const int n4 = (NC * NH * NW) / 4;
    float lmin = 3.4e38f, lmax = -3.4e38f;
    for (int i = blockIdx.x * blockDim.x + threadIdx.x; i < n4; i += gridDim.x * blockDim.x) {
        float4 v = p4[i];
        lmin = fminf(lmin, fminf(fminf(v.x, v.y), fminf(v.z, v.w)));
        lmax = fmaxf(lmax, fmaxf(fmaxf(v.x, v.y), fmaxf(v.z, v.w)));
    }
    #pragma unroll
    for (int off = 32; off; off >>= 1) {
        lmin = fminf(lmin, __shfl_down(lmin, off, 64));
        lmax = fmaxf(lmax, __shfl_down(lmax, off, 64));
    }
    __shared__ float smin[4], smax[4];
    int wid = threadIdx.x >> 6, lane = threadIdx.x & 63;
    if (lane == 0) { smin[wid] = lmin; smax[wid] = lmax; }
    __syncthreads();
    if (threadIdx.x == 0) {
        mnp[b * MMB + blockIdx.x] = fminf(fminf(smin[0], smin[1]), fminf(smin[2], smin[3]));
        mxp[b * MMB + blockIdx.x] = fmaxf(fmaxf(smax[0], smax[1]), fmaxf(smax[2], smax[3]));
    }
}

// -------- kernel 2: R11 structure + enter-own-cols-from-registers
// 2 waves, 512 cols, thread owns 4 cols (= the 4 it stages) / tracks 10.
// 3-set G rotation: row r lives in set r%3 from its load (iter r-3) until
// reload (iter r, AFTER the enter-apply reads it -> WAR by program order).
// Enter needs only the 6-col halo from LDS (2 b128/array); leave = 3 b128.
// LDS ops/thread-iter: 14 -> 12. Slot algebra identical to passing R11:
//   iter k: enter slot k%10 (halo prefetched at k-1), leave slot (k+3)%10
//   (row k-7), stage slot (k+2)%10 (row k+2 from set (k-1)%3).
__global__ __launch_bounds__(128) void ssim_main(const float* __restrict__ tin,
                                                 const float* __restrict__ pin,
                                                 const float* __restrict__ mnp,
                                                 const float* __restrict__ mxp,
                                                 float* __restrict__ bsum) {
    __shared__ float ring[NSLOT][2][NW];   // 40,960 B -> 4 blocks/CU

    const int li    = threadIdx.x;          // 0..127
    const int lane  = li & 63;
    const int imgch = blockIdx.x / NCHK;
    const int chunk = blockIdx.x - imgch * NCHK;
    const int b     = imgch / NC;
    const int r0    = chunk * 24 + max(0, chunk - 19);  // chunks 19,20: 25 rows
    const int rpc   = (chunk >= 19) ? 25 : 24;
    const int kend  = rpc + 6;               // 30 or 31
    const int lastr = rpc + 5;

    // per-image range from 64 partials: butterfly, no LDS
    float mnv = mnp[b * MMB + lane], mxv = mxp[b * MMB + lane];
    #pragma unroll
    for (int m = 1; m < 64; m <<= 1) {
        mnv = fminf(mnv, __shfl_xor(mnv, m, 64));
        mxv = fmaxf(mxv, __shfl_xor(mxv, m, 64));
    }
    const float dr  = mxv - mnv;
    const float c1  = (0.01f * dr) * (0.01f * dr);
    const float c2  = (0.03f * dr) * (0.03f * dr);
    const float C1s = 2401.0f * c1;   // 49^2 * c1
    const float C2s = 2352.0f * c2;   // 48*49 * c2

    const float* tbase = tin + (size_t)imgch * (NH * NW) + (size_t)r0 * NW;
    const float* pbase = pin + (size_t)imgch * (NH * NW) + (size_t)r0 * NW;

    // staging cols == owned cols: 4li..4li+3
    const int scol = 4 * li;                 // 0..508
    const int rc   = scol;
    const int cb1  = min(rc + 4, NW - 4);    // halo cols rc+4..rc+7
    const int cb2  = min(rc + 8, NW - 4);    // halo cols rc+8..rc+9 (first 2 used)

    float st[10], sp[10], stt[10], spp[10], stp[10];
    #pragma unroll
    for (int i = 0; i < 10; ++i) { st[i]=0.f; sp[i]=0.f; stt[i]=0.f; spp[i]=0.f; stp[i]=0.f; }
    float acc = 0.f;

#define UPD1(I, T_, P_, SGN) do {                                   \
        float t_ = (T_), p_ = (P_);                                 \
        st[I]  += SGN t_;  sp[I]  += SGN p_;                        \
        stt[I] = fmaf(SGN t_, t_, stt[I]);                          \
        spp[I] = fmaf(SGN p_, p_, spp[I]);                          \
        stp[I] = fmaf(SGN t_, p_, stp[I]);                          \
    } while (0)

    // enter: own 4 cols from G-regs + 6 halo cols from prefetched regs
#define APPLY_ENTER(GT, GP) do {                                    \
        UPD1(0, GT.x, GP.x, +); UPD1(1, GT.y, GP.y, +);             \
        UPD1(2, GT.z, GP.z, +); UPD1(3, GT.w, GP.w, +);             \
        UPD1(4, ht[0], hp[0], +); UPD1(5, ht[1], hp[1], +);         \
        UPD1(6, ht[2], hp[2], +); UPD1(7, ht[3], hp[3], +);         \
        UPD1(8, ht[4], hp[4], +); UPD1(9, ht[5], hp[5], +);         \
    } while (0)

#define HALO_PREFETCH(S) do {                                       \
        *(float4*)&ht[0] = *(const float4*)&ring[S][0][cb1];        \
        *(float4*)&ht[4] = *(const float4*)&ring[S][0][cb2];        \
        *(float4*)&hp[0] = *(const float4*)&ring[S][1][cb1];        \
        *(float4*)&hp[4] = *(const float4*)&ring[S][1][cb2];        \
    } while (0)

#define LOADFULL(TE, PE, S) do {                                    \
        *(float4*)&TE[0] = *(const float4*)&ring[S][0][rc];         \
        *(float4*)&TE[4] = *(const float4*)&ring[S][0][cb1];        \
        *(float4*)&TE[8] = *(const float4*)&ring[S][0][cb2];        \
        *(float4*)&PE[0] = *(const float4*)&ring[S][1][rc];         \
        *(float4*)&PE[4] = *(const float4*)&ring[S][1][cb1];        \
        *(float4*)&PE[8] = *(const float4*)&ring[S][1][cb2];        \
    } while (0)

#define APPLY_LEAVE(TE, PE) do {                                    \
        UPD1(0, TE[0], PE[0], -); UPD1(1, TE[1], PE[1], -);         \
        UPD1(2, TE[2], PE[2], -); UPD1(3, TE[3], PE[3], -);         \
        UPD1(4, TE[4], PE[4], -); UPD1(5, TE[5], PE[5], -);         \
        UPD1(6, TE[6], PE[6], -); UPD1(7, TE[7], PE[7], -);         \
        UPD1(8, TE[8], PE[8], -); UPD1(9, TE[9], PE[9], -);         \
    } while (0)

#define SSIMADD(C) do {                                             \
        if (rc + (C) < OUTW) {                                      \
            float p12 = S1 * S2;                                    \
            float q1  = S1 * S1, q2 = S2 * S2;                      \
            float Aa  = fmaf(2.f, p12, C1s);                        \
            float Bb  = q1 + q2 + C1s;                              \
            float mtp = fmaf(49.f, S5, -p12);                       \
            float Ac  = fmaf(2.f, mtp, C2s);                        \
            float mtt = fmaf(49.f, S3, -q1);                        \
            float mpp = fmaf(49.f, S4, -q2);                        \
            float Bd  = mtt + mpp + C2s;                            \
            acc += __fdividef(Aa * Ac, Bb * Bd);                    \
        }                                                           \
    } while (0)

#define EMIT do {                                                   \
        float S1 = st[0]+st[1]+st[2]+st[3]+st[4]+st[5]+st[6];       \
        float S2 = sp[0]+sp[1]+sp[2]+sp[3]+sp[4]+sp[5]+sp[6];       \
        float S3 = stt[0]+stt[1]+stt[2]+stt[3]+stt[4]+stt[5]+stt[6];\
        float S4 = spp[0]+spp[1]+spp[2]+spp[3]+spp[4]+spp[5]+spp[6];\
        float S5 = stp[0]+stp[1]+stp[2]+stp[3]+stp[4]+stp[5]+stp[6];\
        SSIMADD(0);                                                 \
        _Pragma("unroll")                                           \
        for (int c = 1; c < 4; ++c) {                               \
            S1 += st[c+6]  - st[c-1];                               \
            S2 += sp[c+6]  - sp[c-1];                               \
            S3 += stt[c+6] - stt[c-1];                              \
            S4 += spp[c+6] - spp[c-1];                              \
            S5 += stp[c+6] - stp[c-1];                              \
            SSIMADD(c);                                             \
        }                                                           \
    } while (0)

    // STEP(K, CUR, PREV): CUR = set k%3 (enter source, then reloaded),
    // PREV = set (k-1)%3 (holds row K+2, staged now).
#define STEP_IMPL(K, CT, CP, PT, PP) do {                           \
        /* 1) stage row K+2 from PREV set (loaded at iter K-1) */   \
        if ((K) + 2 <= lastr) {                                     \
            *(float4*)&ring[sw][0][scol] = PT;                      \
            *(float4*)&ring[sw][1][scol] = PP;                      \
        }                                                           \
        /* 2) leave-reads issued early */                           \
        float lt[12], lp[12];                                       \
        if ((K) >= 7) LOADFULL(lt, lp, slv);                        \
        /* 3) enter row K: own cols from CUR regs + halo regs */    \
        APPLY_ENTER(CT, CP);                                        \
        /* 4) reload CUR with row K+3 (WAR: after apply) */         \
        if ((K) + 3 <= lastr) {                                     \
            CT = *(const float4*)(tbase + (size_t)((K) + 3) * NW + scol); \
            CP = *(const float4*)(pbase + (size_t)((K) + 3) * NW + scol); \
        }                                                           \
        /* 5) halo-prefetch row K+1 (staged at iter K-1) */         \
        if ((K) + 1 < kend) HALO_PREFETCH(sn);                      \
        /* 6) leave row K-7 */                                      \
        if ((K) >= 7) APPLY_LEAVE(lt, lp);                          \
        /* 7) emit row K-6 */                                       \
        if ((K) >= 6) { EMIT; }                                     \
        __syncthreads();                                            \
        if (++sn  == NSLOT) sn  = 0;                                \
        if (++sw  == NSLOT) sw  = 0;                                \
        if (++slv == NSLOT) slv = 0;                                \
    } while (0)

    // prologue: rows 0,1 -> sets A,B and slots 0,1; row 2 -> set C
    float4 gtA, gpA, gtB, gpB, gtC, gpC;
    gtA = *(const float4*)(tbase + scol);
    gpA = *(const float4*)(pbase + scol);
    *(float4*)&ring[0][0][scol] = gtA;
    *(float4*)&ring[0][1][scol] = gpA;
    gtB = *(const float4*)(tbase + NW + scol);
    gpB = *(const float4*)(pbase + NW + scol);
    *(float4*)&ring[1][0][scol] = gtB;
    *(float4*)&ring[1][1][scol] = gpB;
    gtC = *(const float4*)(tbase + 2 * NW + scol);
    gpC = *(const float4*)(pbase + 2 * NW + scol);
    __syncthreads();

    float ht[8], hp[8];
    HALO_PREFETCH(0);                        // halo of row 0

    int sn = 1, sw = 2, slv = 3;             // (k+1)%10, (k+2)%10, (k+3)%10
    int k = 0;
    while (true) {
        STEP_IMPL(k, gtA, gpA, gtC, gpC); if (++k >= kend) break;
        STEP_IMPL(k, gtB, gpB, gtA, gpA); if (++k >= kend) break;
        STEP_IMPL(k, gtC, gpC, gtB, gpB); if (++k >= kend) break;
    }

#undef STEP_IMPL
#undef EMIT
#undef SSIMADD
#undef APPLY_LEAVE
#undef LOADFULL
#undef HALO_PREFETCH
#undef APPLY_ENTER
#undef UPD1

    // per-block partial (deterministic); ring is dead after last barrier
    #pragma unroll
    for (int off = 32; off; off >>= 1) acc += __shfl_down(acc, off, 64);
    if (lane == 0) ((float*)ring)[li >> 6] = acc;
    __syncthreads();
    if (li == 0) {
        float* r = (float*)ring;
        bsum[blockIdx.x] = r[0] + r[1];
    }
}

// -------- kernel 3: finalize per-image mean from 63 block partials
__global__ void ssim_finalize(const float* __restrict__ bsum, float* __restrict__ out) {
    int b = blockIdx.x, lane = threadIdx.x;   // 64 threads
    float v = (lane < BPI) ? bsum[b * BPI + lane] : 0.0f;
    #pragma unroll
    for (int off = 32; off; off >>= 1) v += __shfl_down(v, off, 64);
    if (lane == 0) out[b] = v / (float)(NC * OUTH * OUTW);
}

extern "C" void kernel_launch(void* const* d_in, const int* in_sizes, int n_in,
                              void* d_out, int out_size, void* d_ws, size_t ws_size,
                              hipStream_t stream) {
    const float* t = (const float*)d_in[0];   // true
    const float* p = (const float*)d_in[1];   // pred
    float* out = (float*)d_out;

    float* mnp  = (float*)d_ws;               // 1024 floats
    float* mxp  = mnp + NB * MMB;             // 1024 floats
    float* bsum = mxp + NB * MMB;             // 1008 floats

    ssim_minmax<<<dim3(MMB, NB), 256, 0, stream>>>(p, mnp, mxp);
    // 1008 two-wave blocks (16 img x 3 ch x 21 row-chunks), 40 KB LDS
    ssim_main<<<dim3(NBLK), 128, 0, stream>>>(t, p, mnp, mxp, bsum);
    ssim_finalize<<<dim3(NB), 64, 0, stream>>>(bsum, out);
}